// Round 10
// baseline (54.966 us; speedup 1.0000x reference)
//
#include <hip/hip_runtime.h>

#define BATCH 4
#define CH    128
#define HW    128
#define PAD   10
#define PW    148        // x2b rows (128 + 2*10)
#define PWC   160        // x2b row stride in cols (reads up to col 159 stay in-bounds)
#define WIN   21
#define NUV   441

typedef short s16x8 __attribute__((ext_vector_type(8)));
typedef float f32x4 __attribute__((ext_vector_type(4)));
typedef unsigned short u16x8 __attribute__((ext_vector_type(8)));

static __device__ __forceinline__ unsigned short f32_to_bf16(float f) {
    unsigned int u = __float_as_uint(f);
    u += 0x7FFFu + ((u >> 16) & 1u);       // RNE
    return (unsigned short)(u >> 16);
}

// -------- transpose+convert: x[b][c][i][j] f32 -> channels-last bf16 (proven) --------
// blocks [0,2048): x1 -> x1b [4][128][128][128]
// blocks [2048,4096): x2 -> x2b [4][148][160][128] at +PAD offsets.
// x2b borders NEVER written (garbage); mfma epilogue masks those outputs to 0.
__global__ __launch_bounds__(256) void corr_transpose_kernel(
    const float* __restrict__ x1, const float* __restrict__ x2,
    unsigned short* __restrict__ x1b, unsigned short* __restrict__ x2b)
{
    __shared__ float lds[128][33];       // 16.9 KB
    int bidx  = blockIdx.x;
    int which = bidx >= 2048;
    if (which) bidx -= 2048;
    int jt = bidx & 3;
    int i  = (bidx >> 2) & 127;
    int b  = bidx >> 9;
    int j0 = jt * 32;
    int t  = threadIdx.x;

    const float* __restrict__ src = which ? x2 : x1;

    // phase 1: 128 c-rows x 32 j, one float4 per thread per iter (coalesced 128 B/row)
    int cl = t >> 3, jq = t & 7;
    #pragma unroll
    for (int it = 0; it < 4; ++it) {
        int c = it * 32 + cl;
        float4 vv = *(const float4*)&src[(((size_t)b * CH + c) * HW + i) * HW + j0 + jq * 4];
        lds[c][jq * 4 + 0] = vv.x;
        lds[c][jq * 4 + 1] = vv.y;
        lds[c][jq * 4 + 2] = vv.z;
        lds[c][jq * 4 + 3] = vv.w;
    }
    __syncthreads();

    // phase 2: thread -> (j, 8 c's); 16 threads/j-row x 16 B = 256 B dense rows
    int jl = t >> 4, cg = t & 15;
    #pragma unroll
    for (int it = 0; it < 2; ++it) {
        int j = it * 16 + jl;
        u16x8 o;
        #pragma unroll
        for (int k = 0; k < 8; ++k) o[k] = f32_to_bf16(lds[cg * 8 + k][j]);
        if (!which)
            *(u16x8*)&x1b[(((size_t)b * HW + i) * HW + j0 + j) * CH + cg * 8] = o;
        else
            *(u16x8*)&x2b[(((size_t)b * PW + i + PAD) * PWC + (j0 + j + PAD)) * CH + cg * 8] = o;
    }
}

// -------- correlation GEMM: quarter-pipelined B, raw barrier, counted vmcnt --------
// grid: 6144 = 4 b x 32 ti x 8 tj x 6 z (XCD-swizzled). block: 256 thr = 4 waves.
// Pixel tile 4x16 (M=64, mt == dpi). Wave owns region row rr = z*4+w.
// A tile (16 KB) via glds + XOR swizzle. B staged wave-private in FOUR 32-ch
// quarters (48 q x 64 B = 3 KB, 3 glds each) through 2 buffers. Raw s_barrier
// waits only A (vmcnt(6)); B quarters stay in flight across it. Q2/Q3 issued
// between kc phases; counted vmcnt(3)/vmcnt(0) -> latency covered by MFMAs +
// 4 blocks/CU TLP (LDS = 40 KB exactly). Epilogue: CT overlay, masked stores.
__global__ __launch_bounds__(256, 4) void corr_mfma_kernel(
    const unsigned short* __restrict__ x1b,
    const unsigned short* __restrict__ x2b,
    float* __restrict__ out)
{
    __shared__ unsigned short ldsA[64 * 128];        // 16 KB, chunk-swizzled
    __shared__ unsigned short ldsB[4 * 2 * 1536];    // 24 KB: 4 waves x 2 bufs x (48q x 32ch)

    int bid  = blockIdx.x;
    int swz  = (bid & 7) * 768 + (bid >> 3);   // XCD-contiguous chunks (6144 % 8 == 0)
    int z    = swz % 6;
    int rest = swz / 6;                        // 0..1023
    int tj   = rest & 7;
    int ti   = (rest >> 3) & 31;
    int b    = rest >> 8;
    int i0 = ti * 4, j0 = tj * 16;

    int t    = threadIdx.x;
    int lane = t & 63;
    int w    = t >> 6;             // wave 0..3
    int l15  = lane & 15;
    int lhi  = lane >> 4;          // 0..3
    int rr   = z * 4 + w;          // owned region row, 0..23

    const unsigned short* rowbase =
        x2b + (((size_t)b * PW + i0 + rr) * PWC + j0) * CH;
    unsigned short* buf0 = ldsB + (w * 2 + 0) * 1536;
    unsigned short* buf1 = ldsB + (w * 2 + 1) * 1536;

    // B staging lane decomposition: 16 q x 4 chunks (64 B quarter-rows)
    int qs = lane >> 2;                  // q within 16-group
    int ck = lane & 3;                   // dest chunk slot
    int hB = ck ^ (qs & 3);              // pre-swizzled source chunk (linear LDS dest)

    // quarter issue: 3 glds covering q in [0,48) for ch [qt*32, qt*32+32)
    #define ISSUE_QUARTER(buf, qt)                                                     \
        _Pragma("unroll")                                                              \
        for (int g = 0; g < 3; ++g) {                                                  \
            const unsigned short* srcp =                                               \
                rowbase + (size_t)(g * 16 + qs) * CH + (qt) * 32 + hB * 8;             \
            __builtin_amdgcn_global_load_lds(                                          \
                (const __attribute__((address_space(1))) void*)srcp,                   \
                (__attribute__((address_space(3))) void*)((buf) + g * 512),            \
                16, 0, 0);                                                             \
        }

    // ---- issue A tile (oldest: 4 glds), then Q0, Q1 ----
    #pragma unroll
    for (int it = 0; it < 4; ++it) {
        int s   = w * 4 + it;          // 0..15
        int dpi = s >> 2;
        int pl  = lane >> 4;
        int hs  = lane & 15;           // dest chunk slot
        int p   = s * 4 + pl;
        int dpj = (s & 3) * 4 + pl;
        int h   = hs ^ (p & 7);        // pre-swizzled global source chunk
        const unsigned short* srcp =
            x1b + (((size_t)b * HW + i0 + dpi) * HW + j0 + dpj) * CH + h * 8;
        __builtin_amdgcn_global_load_lds(
            (const __attribute__((address_space(1))) void*)srcp,
            (__attribute__((address_space(3))) void*)(ldsA + s * 512),
            16, 0, 0);
    }
    ISSUE_QUARTER(buf0, 0)
    ISSUE_QUARTER(buf1, 1)

    // ---- raw barrier: wait only A (oldest 4); B quarters stay in flight ----
    __builtin_amdgcn_sched_barrier(0);
    asm volatile("s_waitcnt vmcnt(6)" ::: "memory");
    __builtin_amdgcn_sched_barrier(0);
    __builtin_amdgcn_s_barrier();
    __builtin_amdgcn_sched_barrier(0);

    f32x4 acc[3][4];
    #pragma unroll
    for (int ntl = 0; ntl < 3; ++ntl)
        #pragma unroll
        for (int mt = 0; mt < 4; ++mt)
            acc[ntl][mt] = (f32x4)(0.0f);

    const int q0tab[3] = {0, 16, 20};

    // one kc step: A from ldsA (16-slot swizzle), B from quarter buffer (4-slot swizzle)
    #define KC_STEP(kc, buf)                                                           \
        {                                                                              \
            s16x8 a[4], bb[3];                                                         \
            _Pragma("unroll")                                                          \
            for (int mt = 0; mt < 4; ++mt) {                                           \
                int slot = ((kc) * 4 + lhi) ^ (l15 & 7);                               \
                a[mt] = *(const s16x8*)(ldsA + (mt * 16 + l15) * 128 + slot * 8);      \
            }                                                                          \
            _Pragma("unroll")                                                          \
            for (int ntl = 0; ntl < 3; ++ntl) {                                        \
                int q    = q0tab[ntl] + l15;                                           \
                int slot = lhi ^ (q & 3);                                              \
                bb[ntl] = *(const s16x8*)((buf) + q * 32 + slot * 8);                  \
            }                                                                          \
            __builtin_amdgcn_s_setprio(1);                                             \
            _Pragma("unroll")                                                          \
            for (int ntl = 0; ntl < 3; ++ntl)                                          \
                _Pragma("unroll")                                                      \
                for (int mt = 0; mt < 4; ++mt)                                         \
                    acc[ntl][mt] = __builtin_amdgcn_mfma_f32_16x16x32_bf16(            \
                        a[mt], bb[ntl], acc[ntl][mt], 0, 0, 0);                        \
            __builtin_amdgcn_s_setprio(0);                                             \
        }

    // kc0 from buf0 (Q0 done at vmcnt(3))
    asm volatile("s_waitcnt vmcnt(3)" ::: "memory");
    __builtin_amdgcn_sched_barrier(0);
    KC_STEP(0, buf0)
    __builtin_amdgcn_sched_barrier(0);

    // Q1 done; reuse buf0 for Q2 (kc0's reads retired before its MFMAs issued)
    asm volatile("s_waitcnt vmcnt(0)" ::: "memory");
    __builtin_amdgcn_sched_barrier(0);
    ISSUE_QUARTER(buf0, 2)
    __builtin_amdgcn_sched_barrier(0);

    // kc1 from buf1 (Q1 already drained)
    KC_STEP(1, buf1)
    __builtin_amdgcn_sched_barrier(0);

    // issue Q3 over buf1, then wait Q2 (oldest 3 of 6)
    ISSUE_QUARTER(buf1, 3)
    __builtin_amdgcn_sched_barrier(0);
    asm volatile("s_waitcnt vmcnt(3)" ::: "memory");
    __builtin_amdgcn_sched_barrier(0);
    KC_STEP(2, buf0)
    __builtin_amdgcn_sched_barrier(0);

    // wait Q3, final kc
    asm volatile("s_waitcnt vmcnt(0)" ::: "memory");
    __builtin_amdgcn_sched_barrier(0);
    KC_STEP(3, buf1)

    // ---- wave-private epilogue: CT scratch overlays this wave's buf0+buf1 ----
    float (*myCT)[20] = (float(*)[20])buf0;   // 36 x 20 f32 = 2880 B < 3072 B (buf0)
    #pragma unroll
    for (int dpi = 0; dpi < 4; ++dpi) {
        int u = rr - dpi;                       // wave-uniform
        if ((unsigned)u < 21u) {
            int r2 = i0 + dpi + u - PAD;        // x2 image row (wave-uniform)
            // dump slice transposed: 4 consecutive dpj (lhi*4+reg) at qc = q0+l15
            #pragma unroll
            for (int ntl = 0; ntl < 3; ++ntl)
                *(f32x4*)&myCT[q0tab[ntl] + l15][lhi * 4] = acc[ntl][dpi];
            // diagonal read (dpj=l15, qc=l15+v), masked coalesced stores
            #pragma unroll
            for (int vb = 0; vb < 6; ++vb) {
                int v = vb * 4 + lhi;
                if (v < 21) {
                    int c2 = j0 + l15 + v - PAD;    // x2 image col (per-lane)
                    float val = myCT[l15 + v][l15];
                    if ((unsigned)r2 >= 128u || (unsigned)c2 >= 128u) val = 0.0f;
                    out[(((size_t)b * NUV + u * WIN + v) * HW + (i0 + dpi)) * HW + j0 + l15] = val;
                }
            }
        }
    }
    #undef KC_STEP
    #undef ISSUE_QUARTER
}

extern "C" void kernel_launch(void* const* d_in, const int* in_sizes, int n_in,
                              void* d_out, int out_size, void* d_ws, size_t ws_size,
                              hipStream_t stream) {
    const float* x1 = (const float*)d_in[0];
    const float* x2 = (const float*)d_in[1];
    float* out = (float*)d_out;

    const size_t X1B_ELEMS = (size_t)BATCH * HW * HW * CH;          // 8,388,608
    const size_t X2B_ELEMS = (size_t)BATCH * PW * PWC * CH;         // 12,124,160
    if (ws_size < (X1B_ELEMS + X2B_ELEMS) * sizeof(unsigned short)) return;

    unsigned short* x1b = (unsigned short*)d_ws;
    unsigned short* x2b = x1b + X1B_ELEMS;

    // No zero-fill: x2b pad region stays garbage; epilogue masks those outputs to 0.
    corr_transpose_kernel<<<4096, 256, 0, stream>>>(x1, x2, x1b, x2b);
    corr_mfma_kernel<<<6144, 256, 0, stream>>>(x1b, x2b, out);
}

// Round 11
// 54.175 us; speedup vs baseline: 1.0146x; 1.0146x over previous
//
#include <hip/hip_runtime.h>

#define BATCH 4
#define CH    128
#define HW    128
#define PAD   10
#define PW    148        // x2b rows (128 + 2*10)
#define PWC   160        // x2b row stride in cols (reads up to col 159 stay in-bounds)
#define WIN   21
#define NUV   441
#define NQS   40         // staged B cols per wave per half (q<=35 used; 36-39 pad, in-bounds)

typedef short s16x8 __attribute__((ext_vector_type(8)));
typedef float f32x4 __attribute__((ext_vector_type(4)));
typedef unsigned short u16x8 __attribute__((ext_vector_type(8)));

static __device__ __forceinline__ unsigned short f32_to_bf16(float f) {
    unsigned int u = __float_as_uint(f);
    u += 0x7FFFu + ((u >> 16) & 1u);       // RNE
    return (unsigned short)(u >> 16);
}

// -------- transpose+convert: x[b][c][i][j] f32 -> channels-last bf16 (proven) --------
// blocks [0,2048): x1 -> x1b [4][128][128][128]
// blocks [2048,4096): x2 -> x2b [4][148][160][128] at +PAD offsets.
// x2b borders NEVER written (garbage); mfma epilogue masks those outputs to 0.
__global__ __launch_bounds__(256) void corr_transpose_kernel(
    const float* __restrict__ x1, const float* __restrict__ x2,
    unsigned short* __restrict__ x1b, unsigned short* __restrict__ x2b)
{
    __shared__ float lds[128][33];       // 16.9 KB
    int bidx  = blockIdx.x;
    int which = bidx >= 2048;
    if (which) bidx -= 2048;
    int jt = bidx & 3;
    int i  = (bidx >> 2) & 127;
    int b  = bidx >> 9;
    int j0 = jt * 32;
    int t  = threadIdx.x;

    const float* __restrict__ src = which ? x2 : x1;

    // phase 1: 128 c-rows x 32 j, one float4 per thread per iter (coalesced 128 B/row)
    int cl = t >> 3, jq = t & 7;
    #pragma unroll
    for (int it = 0; it < 4; ++it) {
        int c = it * 32 + cl;
        float4 vv = *(const float4*)&src[(((size_t)b * CH + c) * HW + i) * HW + j0 + jq * 4];
        lds[c][jq * 4 + 0] = vv.x;
        lds[c][jq * 4 + 1] = vv.y;
        lds[c][jq * 4 + 2] = vv.z;
        lds[c][jq * 4 + 3] = vv.w;
    }
    __syncthreads();

    // phase 2: thread -> (j, 8 c's); 16 threads/j-row x 16 B = 256 B dense rows
    int jl = t >> 4, cg = t & 15;
    #pragma unroll
    for (int it = 0; it < 2; ++it) {
        int j = it * 16 + jl;
        u16x8 o;
        #pragma unroll
        for (int k = 0; k < 8; ++k) o[k] = f32_to_bf16(lds[cg * 8 + k][j]);
        if (!which)
            *(u16x8*)&x1b[(((size_t)b * HW + i) * HW + j0 + j) * CH + cg * 8] = o;
        else
            *(u16x8*)&x2b[(((size_t)b * PW + i + PAD) * PWC + (j0 + j + PAD)) * CH + cg * 8] = o;
    }
}

// -------- correlation GEMM (R8 structure, 8-wave z-merged, counted-vmcnt barrier) --------
// grid: 3072 = 4 b x 32 ti x 8 tj x 3 zp (XCD-swizzled). block: 512 thr = 8 waves.
// Pixel tile 4x16 (M=64, mt == dpi). Wave owns region row rr = zp*8+w (0..23).
// A tile (16 KB) staged cooperatively by 8 waves (2 glds each) + XOR-chunk swizzle.
// B row staged WAVE-PRIVATE in two 64-channel halves (5 KB each: 40 q x 128 B rows
// -> spans all 32 banks, 2-way free). Raw s_barrier after vmcnt(5): waits only A,
// B-half-0 latency hides under the barrier. Half 1 re-staged over the same region
// after a wave-local lgkmcnt(0) (DS per-wave in-order). LDS = 56 KB -> 2 blk/CU
// (16 waves/CU, VGPR-capped anyway). MFMA q0-tiles {0,16,20}.
// Epilogue: wave-private CT restage over own B region, masked coalesced stores
// (out-of-image x2 positions -> exact 0.0, replacing zero-padding).
__global__ __launch_bounds__(512, 4) void corr_mfma_kernel(
    const unsigned short* __restrict__ x1b,
    const unsigned short* __restrict__ x2b,
    float* __restrict__ out)
{
    __shared__ unsigned short ldsA[64 * 128];        // 16 KB, chunk-swizzled
    __shared__ unsigned short ldsB[8 * NQS * 64];    // 40 KB (8 waves x 5 KB)

    int bid  = blockIdx.x;
    int swz  = (bid & 7) * 384 + (bid >> 3);   // XCD-contiguous chunks (3072 % 8 == 0)
    int zp   = swz % 3;
    int rest = swz / 3;                        // 0..1023
    int tj   = rest & 7;
    int ti   = (rest >> 3) & 31;
    int b    = rest >> 8;
    int i0 = ti * 4, j0 = tj * 16;

    int t    = threadIdx.x;
    int lane = t & 63;
    int w    = t >> 6;             // wave 0..7
    int l15  = lane & 15;
    int lhi  = lane >> 4;          // 0..3
    int rr   = zp * 8 + w;         // owned region row, 0..23

    const unsigned short* rowbase =
        x2b + (((size_t)b * PW + i0 + rr) * PWC + j0) * CH;
    unsigned short* myB = ldsB + w * (NQS * 64);

    // B staging lane decomposition: 8 q per glds (128 B per q-half-row)
    int bq  = lane >> 3;                 // q within 8-group, 0..7
    int bc2 = (lane & 7) ^ bq;           // pre-swizzled source chunk (linear LDS dest)

    // ---- stage A tile FIRST (oldest in vmcnt order): 2 glds per wave ----
    #pragma unroll
    for (int it = 0; it < 2; ++it) {
        int s   = w * 2 + it;          // 0..15
        int dpi = s >> 2;
        int pl  = lane >> 4;
        int hs  = lane & 15;           // dest chunk slot
        int p   = s * 4 + pl;
        int dpj = (s & 3) * 4 + pl;
        int h   = hs ^ (p & 7);        // pre-swizzled global source chunk
        const unsigned short* srcp =
            x1b + (((size_t)b * HW + i0 + dpi) * HW + j0 + dpj) * CH + h * 8;
        __builtin_amdgcn_global_load_lds(
            (const __attribute__((address_space(1))) void*)srcp,
            (__attribute__((address_space(3))) void*)(ldsA + s * 512),
            16, 0, 0);
    }

    // ---- stage B half 0 (ch 0..63): 5 glds, wave-private ----
    #pragma unroll
    for (int g = 0; g < 5; ++g) {
        int q = g * 8 + bq;
        const unsigned short* srcp = rowbase + (size_t)q * CH + bc2 * 8;
        __builtin_amdgcn_global_load_lds(
            (const __attribute__((address_space(1))) void*)srcp,
            (__attribute__((address_space(3))) void*)(myB + g * 512),
            16, 0, 0);
    }

    // ---- counted barrier: wait only own A (oldest 2 of 7); B0 flies through ----
    __builtin_amdgcn_sched_barrier(0);
    asm volatile("s_waitcnt vmcnt(5)" ::: "memory");
    __builtin_amdgcn_sched_barrier(0);
    __builtin_amdgcn_s_barrier();          // all waves' A now staged
    __builtin_amdgcn_sched_barrier(0);
    asm volatile("s_waitcnt vmcnt(0)" ::: "memory");   // own B0 (latency hid under barrier)
    __builtin_amdgcn_sched_barrier(0);

    f32x4 acc[3][4];
    #pragma unroll
    for (int ntl = 0; ntl < 3; ++ntl)
        #pragma unroll
        for (int mt = 0; mt < 4; ++mt)
            acc[ntl][mt] = (f32x4)(0.0f);

    const int q0tab[3] = {0, 16, 20};

    #pragma unroll
    for (int ph = 0; ph < 2; ++ph) {
        if (ph == 1) {
            // wave-local: all ph0 fragment ds_reads complete, then overwrite myB
            asm volatile("s_waitcnt lgkmcnt(0)" ::: "memory");
            __builtin_amdgcn_sched_barrier(0);
            #pragma unroll
            for (int g = 0; g < 5; ++g) {
                int q = g * 8 + bq;
                const unsigned short* srcp = rowbase + (size_t)q * CH + 64 + bc2 * 8;
                __builtin_amdgcn_global_load_lds(
                    (const __attribute__((address_space(1))) void*)srcp,
                    (__attribute__((address_space(3))) void*)(myB + g * 512),
                    16, 0, 0);
            }
            asm volatile("s_waitcnt vmcnt(0)" ::: "memory");
            __builtin_amdgcn_sched_barrier(0);
        }
        #pragma unroll
        for (int kc2 = 0; kc2 < 2; ++kc2) {
            int kc = ph * 2 + kc2;
            s16x8 a[4], bb[3];
            #pragma unroll
            for (int mt = 0; mt < 4; ++mt) {
                int slot = (kc * 4 + lhi) ^ (l15 & 7);
                a[mt] = *(const s16x8*)(ldsA + (mt * 16 + l15) * 128 + slot * 8);
            }
            #pragma unroll
            for (int ntl = 0; ntl < 3; ++ntl) {
                int q    = q0tab[ntl] + l15;
                int slot = (kc2 * 4 + lhi) ^ (q & 7);
                bb[ntl] = *(const s16x8*)(myB + q * 64 + slot * 8);   // 2-way = free
            }
            __builtin_amdgcn_s_setprio(1);
            #pragma unroll
            for (int ntl = 0; ntl < 3; ++ntl)
                #pragma unroll
                for (int mt = 0; mt < 4; ++mt)
                    acc[ntl][mt] = __builtin_amdgcn_mfma_f32_16x16x32_bf16(a[mt], bb[ntl], acc[ntl][mt], 0, 0, 0);
            __builtin_amdgcn_s_setprio(0);
        }
    }

    // ---- wave-private epilogue: CT scratch overlays this wave's B region ----
    float (*myCT)[20] = (float(*)[20])myB;    // 36 x 20 f32 = 2880 B < 5120 B
    #pragma unroll
    for (int dpi = 0; dpi < 4; ++dpi) {
        int u = rr - dpi;                       // wave-uniform
        if ((unsigned)u < 21u) {
            int r2 = i0 + dpi + u - PAD;        // x2 image row (wave-uniform)
            // dump slice transposed: 4 consecutive dpj (lhi*4+reg) at qc = q0+l15
            #pragma unroll
            for (int ntl = 0; ntl < 3; ++ntl)
                *(f32x4*)&myCT[q0tab[ntl] + l15][lhi * 4] = acc[ntl][dpi];
            // diagonal read (dpj=l15, qc=l15+v), masked coalesced stores
            #pragma unroll
            for (int vb = 0; vb < 6; ++vb) {
                int v = vb * 4 + lhi;
                if (v < 21) {
                    int c2 = j0 + l15 + v - PAD;    // x2 image col (per-lane)
                    float val = myCT[l15 + v][l15];
                    if ((unsigned)r2 >= 128u || (unsigned)c2 >= 128u) val = 0.0f;
                    out[(((size_t)b * NUV + u * WIN + v) * HW + (i0 + dpi)) * HW + j0 + l15] = val;
                }
            }
        }
    }
}

extern "C" void kernel_launch(void* const* d_in, const int* in_sizes, int n_in,
                              void* d_out, int out_size, void* d_ws, size_t ws_size,
                              hipStream_t stream) {
    const float* x1 = (const float*)d_in[0];
    const float* x2 = (const float*)d_in[1];
    float* out = (float*)d_out;

    const size_t X1B_ELEMS = (size_t)BATCH * HW * HW * CH;          // 8,388,608
    const size_t X2B_ELEMS = (size_t)BATCH * PW * PWC * CH;         // 12,124,160
    if (ws_size < (X1B_ELEMS + X2B_ELEMS) * sizeof(unsigned short)) return;

    unsigned short* x1b = (unsigned short*)d_ws;
    unsigned short* x2b = x1b + X1B_ELEMS;

    // No zero-fill: x2b pad region stays garbage; epilogue masks those outputs to 0.
    corr_transpose_kernel<<<4096, 256, 0, stream>>>(x1, x2, x1b, x2b);
    corr_mfma_kernel<<<3072, 512, 0, stream>>>(x1b, x2b, out);
}

// Round 14
// 53.309 us; speedup vs baseline: 1.0311x; 1.0162x over previous
//
#include <hip/hip_runtime.h>

#define BATCH 4
#define CH    128
#define HW    128
#define PAD   10
#define PW    148        // x2b rows (128 + 2*10)
#define PWC   160        // x2b row stride in cols (reads up to col 159 stay in-bounds)
#define WIN   21
#define NUV   441
#define NQS   40         // staged B cols per wave per half (q<=35 used; 36-39 pad, in-bounds)

typedef short s16x8 __attribute__((ext_vector_type(8)));
typedef float f32x4 __attribute__((ext_vector_type(4)));
typedef unsigned short u16x8 __attribute__((ext_vector_type(8)));

static __device__ __forceinline__ unsigned short f32_to_bf16(float f) {
    unsigned int u = __float_as_uint(f);
    u += 0x7FFFu + ((u >> 16) & 1u);       // RNE
    return (unsigned short)(u >> 16);
}

// -------- transpose+convert: x[b][c][i][j] f32 -> channels-last bf16 (proven) --------
// blocks [0,2048): x1 -> x1b [4][128][128][128]
// blocks [2048,4096): x2 -> x2b [4][148][160][128] at +PAD offsets.
// x2b borders NEVER written (garbage); mfma epilogue masks those outputs to 0.
__global__ __launch_bounds__(256) void corr_transpose_kernel(
    const float* __restrict__ x1, const float* __restrict__ x2,
    unsigned short* __restrict__ x1b, unsigned short* __restrict__ x2b)
{
    __shared__ float lds[128][33];       // 16.9 KB
    int bidx  = blockIdx.x;
    int which = bidx >= 2048;
    if (which) bidx -= 2048;
    int jt = bidx & 3;
    int i  = (bidx >> 2) & 127;
    int b  = bidx >> 9;
    int j0 = jt * 32;
    int t  = threadIdx.x;

    const float* __restrict__ src = which ? x2 : x1;

    // phase 1: 128 c-rows x 32 j, one float4 per thread per iter (coalesced 128 B/row)
    int cl = t >> 3, jq = t & 7;
    #pragma unroll
    for (int it = 0; it < 4; ++it) {
        int c = it * 32 + cl;
        float4 vv = *(const float4*)&src[(((size_t)b * CH + c) * HW + i) * HW + j0 + jq * 4];
        lds[c][jq * 4 + 0] = vv.x;
        lds[c][jq * 4 + 1] = vv.y;
        lds[c][jq * 4 + 2] = vv.z;
        lds[c][jq * 4 + 3] = vv.w;
    }
    __syncthreads();

    // phase 2: thread -> (j, 8 c's); 16 threads/j-row x 16 B = 256 B dense rows
    int jl = t >> 4, cg = t & 15;
    #pragma unroll
    for (int it = 0; it < 2; ++it) {
        int j = it * 16 + jl;
        u16x8 o;
        #pragma unroll
        for (int k = 0; k < 8; ++k) o[k] = f32_to_bf16(lds[cg * 8 + k][j]);
        if (!which)
            *(u16x8*)&x1b[(((size_t)b * HW + i) * HW + j0 + j) * CH + cg * 8] = o;
        else
            *(u16x8*)&x2b[(((size_t)b * PW + i + PAD) * PWC + (j0 + j + PAD)) * CH + cg * 8] = o;
    }
}

// -------- correlation GEMM (R8 proven structure + R10's counted-barrier prologue) --------
// grid: 6144 = 4 b x 32 ti x 8 tj x 6 z (XCD-swizzled). block: 256 thr = 4 waves.
// Pixel tile 4x16 (M=64, mt == dpi). Wave owns region row rr = z*4+w.
// A tile (16 KB) staged via glds + XOR-chunk swizzle. B row staged WAVE-PRIVATE in
// two 64-channel halves (5 KB each: 40 q x 128 B rows -> spans all 32 banks, 2-way
// free). Prologue: A-glds issued FIRST (glds are LDS-stores -> issue order
// preserved), vmcnt(5) waits only A, raw s_barrier, then wave-local vmcnt(0) for
// B0 (its latency hides under the barrier). Half 1 re-staged over the same region
// after a wave-local lgkmcnt(0) (DS per-wave in-order). LDS = 36 KB -> 4 blk/CU.
// MFMA q0-tiles {0,16,20}. Epilogue: wave-private CT restage, masked stores
// (out-of-image x2 positions -> exact 0.0, replacing zero-padding).
__global__ __launch_bounds__(256, 4) void corr_mfma_kernel(
    const unsigned short* __restrict__ x1b,
    const unsigned short* __restrict__ x2b,
    float* __restrict__ out)
{
    __shared__ unsigned short ldsA[64 * 128];        // 16 KB, chunk-swizzled
    __shared__ unsigned short ldsB[4 * NQS * 64];    // 20 KB (4 waves x 5 KB)

    int bid  = blockIdx.x;
    int swz  = (bid & 7) * 768 + (bid >> 3);   // XCD-contiguous chunks (6144 % 8 == 0)
    int z    = swz % 6;
    int rest = swz / 6;                        // 0..1023
    int tj   = rest & 7;
    int ti   = (rest >> 3) & 31;
    int b    = rest >> 8;
    int i0 = ti * 4, j0 = tj * 16;

    int t    = threadIdx.x;
    int lane = t & 63;
    int w    = t >> 6;             // wave 0..3
    int l15  = lane & 15;
    int lhi  = lane >> 4;          // 0..3
    int rr   = z * 4 + w;          // owned region row, 0..23

    const unsigned short* rowbase =
        x2b + (((size_t)b * PW + i0 + rr) * PWC + j0) * CH;
    unsigned short* myB = ldsB + w * (NQS * 64);

    // B staging lane decomposition: 8 q per glds (128 B per q-half-row)
    int bq  = lane >> 3;                 // q within 8-group, 0..7
    int bc2 = (lane & 7) ^ bq;           // pre-swizzled source chunk (linear LDS dest)

    // ---- stage A tile FIRST (oldest in issue order): 4 glds per wave ----
    #pragma unroll
    for (int it = 0; it < 4; ++it) {
        int s   = w * 4 + it;          // 0..15
        int dpi = s >> 2;
        int pl  = lane >> 4;
        int hs  = lane & 15;           // dest chunk slot
        int p   = s * 4 + pl;
        int dpj = (s & 3) * 4 + pl;
        int h   = hs ^ (p & 7);        // pre-swizzled global source chunk
        const unsigned short* srcp =
            x1b + (((size_t)b * HW + i0 + dpi) * HW + j0 + dpj) * CH + h * 8;
        __builtin_amdgcn_global_load_lds(
            (const __attribute__((address_space(1))) void*)srcp,
            (__attribute__((address_space(3))) void*)(ldsA + s * 512),
            16, 0, 0);
    }

    // ---- stage B half 0 (ch 0..63): 5 glds, wave-private ----
    #pragma unroll
    for (int g = 0; g < 5; ++g) {
        int q = g * 8 + bq;
        const unsigned short* srcp = rowbase + (size_t)q * CH + bc2 * 8;
        __builtin_amdgcn_global_load_lds(
            (const __attribute__((address_space(1))) void*)srcp,
            (__attribute__((address_space(3))) void*)(myB + g * 512),
            16, 0, 0);
    }

    // ---- counted barrier (R10-proven): wait only own A; B0 flies through ----
    asm volatile("s_waitcnt vmcnt(5)" ::: "memory");
    __builtin_amdgcn_sched_barrier(0);
    __builtin_amdgcn_s_barrier();          // all waves' A now staged
    __builtin_amdgcn_sched_barrier(0);
    asm volatile("s_waitcnt vmcnt(0)" ::: "memory");   // own B0 (hid under barrier)
    __builtin_amdgcn_sched_barrier(0);

    f32x4 acc[3][4];
    #pragma unroll
    for (int ntl = 0; ntl < 3; ++ntl)
        #pragma unroll
        for (int mt = 0; mt < 4; ++mt)
            acc[ntl][mt] = (f32x4)(0.0f);

    const int q0tab[3] = {0, 16, 20};

    #pragma unroll
    for (int ph = 0; ph < 2; ++ph) {
        if (ph == 1) {
            // wave-local: all ph0 fragment ds_reads complete, then overwrite myB
            asm volatile("s_waitcnt lgkmcnt(0)" ::: "memory");
            __builtin_amdgcn_sched_barrier(0);
            #pragma unroll
            for (int g = 0; g < 5; ++g) {
                int q = g * 8 + bq;
                const unsigned short* srcp = rowbase + (size_t)q * CH + 64 + bc2 * 8;
                __builtin_amdgcn_global_load_lds(
                    (const __attribute__((address_space(1))) void*)srcp,
                    (__attribute__((address_space(3))) void*)(myB + g * 512),
                    16, 0, 0);
            }
            asm volatile("s_waitcnt vmcnt(0)" ::: "memory");
            __builtin_amdgcn_sched_barrier(0);
        }
        #pragma unroll
        for (int kc2 = 0; kc2 < 2; ++kc2) {
            int kc = ph * 2 + kc2;
            s16x8 a[4], bb[3];
            #pragma unroll
            for (int mt = 0; mt < 4; ++mt) {
                int slot = (kc * 4 + lhi) ^ (l15 & 7);
                a[mt] = *(const s16x8*)(ldsA + (mt * 16 + l15) * 128 + slot * 8);
            }
            #pragma unroll
            for (int ntl = 0; ntl < 3; ++ntl) {
                int q    = q0tab[ntl] + l15;
                int slot = (kc2 * 4 + lhi) ^ (q & 7);
                bb[ntl] = *(const s16x8*)(myB + q * 64 + slot * 8);   // 2-way = free
            }
            __builtin_amdgcn_s_setprio(1);
            #pragma unroll
            for (int ntl = 0; ntl < 3; ++ntl)
                #pragma unroll
                for (int mt = 0; mt < 4; ++mt)
                    acc[ntl][mt] = __builtin_amdgcn_mfma_f32_16x16x32_bf16(a[mt], bb[ntl], acc[ntl][mt], 0, 0, 0);
            __builtin_amdgcn_s_setprio(0);
        }
    }

    // ---- wave-private epilogue: CT scratch overlays this wave's B region ----
    float (*myCT)[20] = (float(*)[20])myB;    // 36 x 20 f32 = 2880 B < 5120 B
    #pragma unroll
    for (int dpi = 0; dpi < 4; ++dpi) {
        int u = rr - dpi;                       // wave-uniform
        if ((unsigned)u < 21u) {
            int r2 = i0 + dpi + u - PAD;        // x2 image row (wave-uniform)
            // dump slice transposed: 4 consecutive dpj (lhi*4+reg) at qc = q0+l15
            #pragma unroll
            for (int ntl = 0; ntl < 3; ++ntl)
                *(f32x4*)&myCT[q0tab[ntl] + l15][lhi * 4] = acc[ntl][dpi];
            // diagonal read (dpj=l15, qc=l15+v), masked coalesced stores
            #pragma unroll
            for (int vb = 0; vb < 6; ++vb) {
                int v = vb * 4 + lhi;
                if (v < 21) {
                    int c2 = j0 + l15 + v - PAD;    // x2 image col (per-lane)
                    float val = myCT[l15 + v][l15];
                    if ((unsigned)r2 >= 128u || (unsigned)c2 >= 128u) val = 0.0f;
                    out[(((size_t)b * NUV + u * WIN + v) * HW + (i0 + dpi)) * HW + j0 + l15] = val;
                }
            }
        }
    }
}

extern "C" void kernel_launch(void* const* d_in, const int* in_sizes, int n_in,
                              void* d_out, int out_size, void* d_ws, size_t ws_size,
                              hipStream_t stream) {
    const float* x1 = (const float*)d_in[0];
    const float* x2 = (const float*)d_in[1];
    float* out = (float*)d_out;

    const size_t X1B_ELEMS = (size_t)BATCH * HW * HW * CH;          // 8,388,608
    const size_t X2B_ELEMS = (size_t)BATCH * PW * PWC * CH;         // 12,124,160
    if (ws_size < (X1B_ELEMS + X2B_ELEMS) * sizeof(unsigned short)) return;

    unsigned short* x1b = (unsigned short*)d_ws;
    unsigned short* x2b = x1b + X1B_ELEMS;

    // No zero-fill: x2b pad region stays garbage; epilogue masks those outputs to 0.
    corr_transpose_kernel<<<4096, 256, 0, stream>>>(x1, x2, x1b, x2b);
    corr_mfma_kernel<<<6144, 256, 0, stream>>>(x1b, x2b, out);
}

// Round 15
// 53.062 us; speedup vs baseline: 1.0359x; 1.0047x over previous
//
#include <hip/hip_runtime.h>

#define BATCH 4
#define CH    128
#define HW    128
#define PAD   10
#define PW    148        // x2b rows (128 + 2*10)
#define PWC   160        // x2b row stride in cols (reads up to col 159 stay in-bounds)
#define WIN   21
#define NUV   441
#define NQS   40         // staged B cols per wave per half (q<=35 used; 36-39 pad, in-bounds)

typedef short s16x8 __attribute__((ext_vector_type(8)));
typedef float f32x4 __attribute__((ext_vector_type(4)));
typedef unsigned short u16x8 __attribute__((ext_vector_type(8)));

static __device__ __forceinline__ unsigned short f32_to_bf16(float f) {
    unsigned int u = __float_as_uint(f);
    u += 0x7FFFu + ((u >> 16) & 1u);       // RNE
    return (unsigned short)(u >> 16);
}

// -------- transpose+convert: x[b][c][i][j] f32 -> channels-last bf16 --------
// blocks [0,2048): x1 -> x1b [4][128][128][128]
// blocks [2048,4096): x2 -> x2b [4][148][160][128] at +PAD offsets.
// x2b borders NEVER written (garbage); mfma epilogue masks those outputs to 0.
// NEW (R14): column swizzle col' = j ^ ((c>>5)&3)*4 (bijective per row, flips
// j-bits 2-3) -> phase-2 read banks become (8b+4a+jl+k) mod 32, max 2-way (free)
// instead of the prior 4-way on all 16 reads/thread. Phase-1 swizzle term is
// wave-uniform -> its write pattern unchanged.
__global__ __launch_bounds__(256) void corr_transpose_kernel(
    const float* __restrict__ x1, const float* __restrict__ x2,
    unsigned short* __restrict__ x1b, unsigned short* __restrict__ x2b)
{
    __shared__ float lds[128][33];       // 16.9 KB
    int bidx  = blockIdx.x;
    int which = bidx >= 2048;
    if (which) bidx -= 2048;
    int jt = bidx & 3;
    int i  = (bidx >> 2) & 127;
    int b  = bidx >> 9;
    int j0 = jt * 32;
    int t  = threadIdx.x;

    const float* __restrict__ src = which ? x2 : x1;

    // phase 1: 128 c-rows x 32 j, one float4 per thread per iter (coalesced 128 B/row)
    int cl = t >> 3, jq = t & 7;
    #pragma unroll
    for (int it = 0; it < 4; ++it) {
        int c   = it * 32 + cl;
        int jqs = jq ^ ((c >> 5) & 3);      // swizzled quad index (wave-uniform term)
        float4 vv = *(const float4*)&src[(((size_t)b * CH + c) * HW + i) * HW + j0 + jq * 4];
        lds[c][jqs * 4 + 0] = vv.x;
        lds[c][jqs * 4 + 1] = vv.y;
        lds[c][jqs * 4 + 2] = vv.z;
        lds[c][jqs * 4 + 3] = vv.w;
    }
    __syncthreads();

    // phase 2: thread -> (j, 8 c's); 16 threads/j-row x 16 B = 256 B dense rows
    int jl = t >> 4, cg = t & 15;
    int sw = cg & 12;                       // = ((c>>3)&12) for c in [8cg, 8cg+8)
    #pragma unroll
    for (int it = 0; it < 2; ++it) {
        int j  = it * 16 + jl;
        int jc = j ^ sw;                    // swizzled column to read
        u16x8 o;
        #pragma unroll
        for (int k = 0; k < 8; ++k) o[k] = f32_to_bf16(lds[cg * 8 + k][jc]);
        if (!which)
            *(u16x8*)&x1b[(((size_t)b * HW + i) * HW + j0 + j) * CH + cg * 8] = o;
        else
            *(u16x8*)&x2b[(((size_t)b * PW + i + PAD) * PWC + (j0 + j + PAD)) * CH + cg * 8] = o;
    }
}

// -------- correlation GEMM (R13 proven, verbatim) --------
// grid: 6144 = 4 b x 32 ti x 8 tj x 6 z (XCD-swizzled). block: 256 thr = 4 waves.
// Pixel tile 4x16 (M=64, mt == dpi). Wave owns region row rr = z*4+w.
// A tile (16 KB) staged via glds + XOR-chunk swizzle. B row staged WAVE-PRIVATE in
// two 64-channel halves (5 KB each: 40 q x 128 B rows). Counted-barrier prologue;
// half 1 re-staged over the same region after a wave-local lgkmcnt(0).
// LDS = 36 KB -> 4 blk/CU. MFMA q0-tiles {0,16,20}. Epilogue: wave-private CT
// restage, masked coalesced stores (out-of-image -> exact 0.0).
__global__ __launch_bounds__(256, 4) void corr_mfma_kernel(
    const unsigned short* __restrict__ x1b,
    const unsigned short* __restrict__ x2b,
    float* __restrict__ out)
{
    __shared__ unsigned short ldsA[64 * 128];        // 16 KB, chunk-swizzled
    __shared__ unsigned short ldsB[4 * NQS * 64];    // 20 KB (4 waves x 5 KB)

    int bid  = blockIdx.x;
    int swz  = (bid & 7) * 768 + (bid >> 3);   // XCD-contiguous chunks (6144 % 8 == 0)
    int z    = swz % 6;
    int rest = swz / 6;                        // 0..1023
    int tj   = rest & 7;
    int ti   = (rest >> 3) & 31;
    int b    = rest >> 8;
    int i0 = ti * 4, j0 = tj * 16;

    int t    = threadIdx.x;
    int lane = t & 63;
    int w    = t >> 6;             // wave 0..3
    int l15  = lane & 15;
    int lhi  = lane >> 4;          // 0..3
    int rr   = z * 4 + w;          // owned region row, 0..23

    const unsigned short* rowbase =
        x2b + (((size_t)b * PW + i0 + rr) * PWC + j0) * CH;
    unsigned short* myB = ldsB + w * (NQS * 64);

    // B staging lane decomposition: 8 q per glds (128 B per q-half-row)
    int bq  = lane >> 3;                 // q within 8-group, 0..7
    int bc2 = (lane & 7) ^ bq;           // pre-swizzled source chunk (linear LDS dest)

    // ---- stage A tile FIRST (oldest in issue order): 4 glds per wave ----
    #pragma unroll
    for (int it = 0; it < 4; ++it) {
        int s   = w * 4 + it;          // 0..15
        int dpi = s >> 2;
        int pl  = lane >> 4;
        int hs  = lane & 15;           // dest chunk slot
        int p   = s * 4 + pl;
        int dpj = (s & 3) * 4 + pl;
        int h   = hs ^ (p & 7);        // pre-swizzled global source chunk
        const unsigned short* srcp =
            x1b + (((size_t)b * HW + i0 + dpi) * HW + j0 + dpj) * CH + h * 8;
        __builtin_amdgcn_global_load_lds(
            (const __attribute__((address_space(1))) void*)srcp,
            (__attribute__((address_space(3))) void*)(ldsA + s * 512),
            16, 0, 0);
    }

    // ---- stage B half 0 (ch 0..63): 5 glds, wave-private ----
    #pragma unroll
    for (int g = 0; g < 5; ++g) {
        int q = g * 8 + bq;
        const unsigned short* srcp = rowbase + (size_t)q * CH + bc2 * 8;
        __builtin_amdgcn_global_load_lds(
            (const __attribute__((address_space(1))) void*)srcp,
            (__attribute__((address_space(3))) void*)(myB + g * 512),
            16, 0, 0);
    }

    // ---- counted barrier: wait only own A; B0 flies through ----
    asm volatile("s_waitcnt vmcnt(5)" ::: "memory");
    __builtin_amdgcn_sched_barrier(0);
    __builtin_amdgcn_s_barrier();          // all waves' A now staged
    __builtin_amdgcn_sched_barrier(0);
    asm volatile("s_waitcnt vmcnt(0)" ::: "memory");   // own B0 (hid under barrier)
    __builtin_amdgcn_sched_barrier(0);

    f32x4 acc[3][4];
    #pragma unroll
    for (int ntl = 0; ntl < 3; ++ntl)
        #pragma unroll
        for (int mt = 0; mt < 4; ++mt)
            acc[ntl][mt] = (f32x4)(0.0f);

    const int q0tab[3] = {0, 16, 20};

    #pragma unroll
    for (int ph = 0; ph < 2; ++ph) {
        if (ph == 1) {
            // wave-local: all ph0 fragment ds_reads complete, then overwrite myB
            asm volatile("s_waitcnt lgkmcnt(0)" ::: "memory");
            __builtin_amdgcn_sched_barrier(0);
            #pragma unroll
            for (int g = 0; g < 5; ++g) {
                int q = g * 8 + bq;
                const unsigned short* srcp = rowbase + (size_t)q * CH + 64 + bc2 * 8;
                __builtin_amdgcn_global_load_lds(
                    (const __attribute__((address_space(1))) void*)srcp,
                    (__attribute__((address_space(3))) void*)(myB + g * 512),
                    16, 0, 0);
            }
            asm volatile("s_waitcnt vmcnt(0)" ::: "memory");
            __builtin_amdgcn_sched_barrier(0);
        }
        #pragma unroll
        for (int kc2 = 0; kc2 < 2; ++kc2) {
            int kc = ph * 2 + kc2;
            s16x8 a[4], bb[3];
            #pragma unroll
            for (int mt = 0; mt < 4; ++mt) {
                int slot = (kc * 4 + lhi) ^ (l15 & 7);
                a[mt] = *(const s16x8*)(ldsA + (mt * 16 + l15) * 128 + slot * 8);
            }
            #pragma unroll
            for (int ntl = 0; ntl < 3; ++ntl) {
                int q    = q0tab[ntl] + l15;
                int slot = (kc2 * 4 + lhi) ^ (q & 7);
                bb[ntl] = *(const s16x8*)(myB + q * 64 + slot * 8);   // 2-way = free
            }
            __builtin_amdgcn_s_setprio(1);
            #pragma unroll
            for (int ntl = 0; ntl < 3; ++ntl)
                #pragma unroll
                for (int mt = 0; mt < 4; ++mt)
                    acc[ntl][mt] = __builtin_amdgcn_mfma_f32_16x16x32_bf16(a[mt], bb[ntl], acc[ntl][mt], 0, 0, 0);
            __builtin_amdgcn_s_setprio(0);
        }
    }

    // ---- wave-private epilogue: CT scratch overlays this wave's B region ----
    float (*myCT)[20] = (float(*)[20])myB;    // 36 x 20 f32 = 2880 B < 5120 B
    #pragma unroll
    for (int dpi = 0; dpi < 4; ++dpi) {
        int u = rr - dpi;                       // wave-uniform
        if ((unsigned)u < 21u) {
            int r2 = i0 + dpi + u - PAD;        // x2 image row (wave-uniform)
            // dump slice transposed: 4 consecutive dpj (lhi*4+reg) at qc = q0+l15
            #pragma unroll
            for (int ntl = 0; ntl < 3; ++ntl)
                *(f32x4*)&myCT[q0tab[ntl] + l15][lhi * 4] = acc[ntl][dpi];
            // diagonal read (dpj=l15, qc=l15+v), masked coalesced stores
            #pragma unroll
            for (int vb = 0; vb < 6; ++vb) {
                int v = vb * 4 + lhi;
                if (v < 21) {
                    int c2 = j0 + l15 + v - PAD;    // x2 image col (per-lane)
                    float val = myCT[l15 + v][l15];
                    if ((unsigned)r2 >= 128u || (unsigned)c2 >= 128u) val = 0.0f;
                    out[(((size_t)b * NUV + u * WIN + v) * HW + (i0 + dpi)) * HW + j0 + l15] = val;
                }
            }
        }
    }
}

extern "C" void kernel_launch(void* const* d_in, const int* in_sizes, int n_in,
                              void* d_out, int out_size, void* d_ws, size_t ws_size,
                              hipStream_t stream) {
    const float* x1 = (const float*)d_in[0];
    const float* x2 = (const float*)d_in[1];
    float* out = (float*)d_out;

    const size_t X1B_ELEMS = (size_t)BATCH * HW * HW * CH;          // 8,388,608
    const size_t X2B_ELEMS = (size_t)BATCH * PW * PWC * CH;         // 12,124,160
    if (ws_size < (X1B_ELEMS + X2B_ELEMS) * sizeof(unsigned short)) return;

    unsigned short* x1b = (unsigned short*)d_ws;
    unsigned short* x2b = x1b + X1B_ELEMS;

    // No zero-fill: x2b pad region stays garbage; epilogue masks those outputs to 0.
    corr_transpose_kernel<<<4096, 256, 0, stream>>>(x1, x2, x1b, x2b);
    corr_mfma_kernel<<<6144, 256, 0, stream>>>(x1b, x2b, out);
}